// Round 15
// baseline (2159.306 us; speedup 1.0000x reference)
//
#include <hip/hip_runtime.h>

// ---- problem constants ----
#define BB 64
#define TLEN 256
#define HH 512
#define GG 1536     // 3*H
#define EPAD 320    // E=300 padded to mult of 64
#define NN 3072     // 2*G (both directions stacked)
#define MM 16384    // T*B

typedef __attribute__((ext_vector_type(8))) __fp16 half8;
typedef __attribute__((ext_vector_type(4))) __fp16 half4;
typedef __attribute__((ext_vector_type(4))) float floatx4;

typedef union { unsigned long long u[2]; half8 v; } hpack;
typedef union { half4 h4; unsigned long long u; } hpack4;
typedef union { unsigned short s; __fp16 h; } hu16;

// ---- FUSED gemm + persistent GRU recurrence (one layer per launch) ----
// grid 3136 = 64 rnn WGs (blockIdx 0..63) + 3072 gemm WGs. The gemm computes
// xp = A x W^T + bias and publishes via 8B AGENT-SCOPE ATOMIC stores (must
// reach LLC — plain stores can sit in the producer XCD's L2 until kernel end
// -> circular wait). The rnn consumes xp[t] per step, validated by the proven
// sentinel-spin (xp can never be 0xFFFF = -NaN: finite dot + bias; fp16
// overflow gives +-inf, not NaN). DEADLOCK-FREE BY CAPACITY regardless of
// dispatch order (G16): rnn holds <=64 CUs, gemm always has >=192 ->
// unconditional progress.
//   * ROUND-15: prep kernel DELETED — conversions folded into gemm staging
//     (lay=0: A = gather emb[x[b,t]] fp32->fp16 with K-pad; W = w_ih0 fp32
//     with pad. lay=1: A = h0 fp16 direct; W = w_ih1 fp32 convert). The gemm
//     is fully hidden under the rnn (4x production margin) -> staging cost
//     is free. Max-pool folded into rnn1 (running fmax of the SAME fp16-
//     rounded publish values -> bit-identical to pooling hx afterwards).
//   * ROUND-14 (kept): GROUP-PIPELINED consumption — 16 h-fragments in 4
//     groups of 4 kk; validate group, run its 12 MFMAs, next group. A
//     straggler blocks only its group; other groups' MFMA runs under its
//     latency. Retries reload only the blocked group. xp validation DEFERRED
//     to after the MFMA loop (epilogue-only inputs).
//   * xp granules for step s+1 PREFETCHED at loop bottom (round-13).
//   * gemm m-tiles extremes-first (t pairs 0,255,1,254,...).
//   * gemm epilogue OPERAND-SWAPPED (round-9 algebra): one aligned 8B word.
//   * rnn = round-8 body; weights in round-11's register-frugal layout (w_r
//     in 64 VGPRs, w_z/w_n in LDS fragment layout, 0 bank conflicts). LDS
//     UNIONED with gemm's As/Ws. hout nullable (layer 1); pooled nullable
//     (layer 0).
__global__ __launch_bounds__(256, 1) void g2_fused(
    const float* __restrict__ whh,    // [2][1536][512] fp32
    const float* __restrict__ bhh,    // [2][1536] fp32
    __fp16* xp,                       // [256][64][3072] gemm writes (atomic), rnn reads (atomic)
    __fp16* __restrict__ hout,        // [256][64][1024] or null
    __fp16* __restrict__ hx,          // [256][2][2][2][8192] (pre-memset 0xFF)
    const __fp16* __restrict__ ga,    // lay=1: gemm A = h0 [16384][1024] fp16
    const float* __restrict__ gwf,    // fp32 ih-weights: [3072][300] or [3072][1024]
    const float* __restrict__ gbias,  // [3072]
    int Kp, int lay,
    const int* __restrict__ gx,       // lay=0: token ids [64][256]
    const float* __restrict__ gemb,   // lay=0: embedding [50000][300] fp32
    float* __restrict__ pooled) {     // lay=1: [64][1024] fp32 out; else null
  __shared__ __align__(16) char smem[65536];
  __shared__ __fp16 hst[4][16][20];
  const unsigned long long SENT = 0xFFFFFFFFFFFFFFFFULL;
  const int bid = blockIdx.x;
  const int tid = threadIdx.x;
  const int lane = tid & 63, wv = tid >> 6;
  const int nsub = lane & 15, quad = lane >> 4;

  if (bid >= 64) {
    // ================= GEMM part: xp = A x W^T + gbias =================
    const int gb = bid - 64;
    const int kb = gb / 24, nb = gb - kb * 24;
    const int mt = (kb & 1) ? (127 - (kb >> 1)) : (kb >> 1);  // extremes first
    const int m0 = mt << 7, n0 = nb << 7;
    __fp16 (*As)[72] = (__fp16(*)[72])smem;
    __fp16 (*Ws)[72] = (__fp16(*)[72])(smem + 18432);
    const int wm = (wv >> 1) << 6, wn = (wv & 1) << 6;
    floatx4 acc[4][4];
#pragma unroll
    for (int i = 0; i < 4; i++)
#pragma unroll
      for (int j = 0; j < 4; j++) acc[i][j] = (floatx4){0.f, 0.f, 0.f, 0.f};
    const int lr = tid >> 3;          // 0..31
    const int lc = (tid & 7) << 3;    // 0..56 step 8
    for (int ko = 0; ko < Kp; ko += 64) {
      const int c0 = ko + lc;
#pragma unroll
      for (int p = 0; p < 4; p++) {
        int r = lr + p * 32;
        if (lay == 0) {
          // A: inline embedding gather + fp32->fp16 + K-pad to 320
          int row = m0 + r;
          int t = row >> 6, b = row & 63;
          int xi = gx[b * TLEN + t];
          const float* er = gemb + (long)xi * 300;
          half8 oa;
          if (c0 + 8 <= 300) {
            float4 a = *(const float4*)&er[c0];
            float4 b2 = *(const float4*)&er[c0 + 4];
            oa[0] = (__fp16)a.x; oa[1] = (__fp16)a.y; oa[2] = (__fp16)a.z; oa[3] = (__fp16)a.w;
            oa[4] = (__fp16)b2.x; oa[5] = (__fp16)b2.y; oa[6] = (__fp16)b2.z; oa[7] = (__fp16)b2.w;
          } else {
#pragma unroll
            for (int q = 0; q < 8; q++) {
              int c = c0 + q;
              oa[q] = (c < 300) ? (__fp16)er[c] : (__fp16)0.f;
            }
          }
          *(half8*)&As[r][lc] = oa;
          // W: w_ih0 fp32 [3072][300] + pad
          const float* wr2 = gwf + (long)(n0 + r) * 300;
          half8 ow;
          if (c0 + 8 <= 300) {
            float4 a = *(const float4*)&wr2[c0];
            float4 b2 = *(const float4*)&wr2[c0 + 4];
            ow[0] = (__fp16)a.x; ow[1] = (__fp16)a.y; ow[2] = (__fp16)a.z; ow[3] = (__fp16)a.w;
            ow[4] = (__fp16)b2.x; ow[5] = (__fp16)b2.y; ow[6] = (__fp16)b2.z; ow[7] = (__fp16)b2.w;
          } else {
#pragma unroll
            for (int q = 0; q < 8; q++) {
              int c = c0 + q;
              ow[q] = (c < 300) ? (__fp16)wr2[c] : (__fp16)0.f;
            }
          }
          *(half8*)&Ws[r][lc] = ow;
        } else {
          // A: h0 fp16 direct; W: w_ih1 fp32 [3072][1024] convert
          *(half8*)&As[r][lc] = *(const half8*)&ga[(long)(m0 + r) * Kp + c0];
          const float* wr2 = gwf + (long)(n0 + r) * 1024;
          float4 a = *(const float4*)&wr2[c0];
          float4 b2 = *(const float4*)&wr2[c0 + 4];
          half8 ow;
          ow[0] = (__fp16)a.x; ow[1] = (__fp16)a.y; ow[2] = (__fp16)a.z; ow[3] = (__fp16)a.w;
          ow[4] = (__fp16)b2.x; ow[5] = (__fp16)b2.y; ow[6] = (__fp16)b2.z; ow[7] = (__fp16)b2.w;
          *(half8*)&Ws[r][lc] = ow;
        }
      }
      __syncthreads();
#pragma unroll
      for (int kk = 0; kk < 64; kk += 32) {
        half8 af[4], bf[4];
        const int kr = kk + (quad << 3);
#pragma unroll
        for (int i = 0; i < 4; i++) af[i] = *(const half8*)&As[wm + i * 16 + nsub][kr];
#pragma unroll
        for (int j = 0; j < 4; j++) bf[j] = *(const half8*)&Ws[wn + j * 16 + nsub][kr];
        // SWAPPED: lane -> (row = nsub of af[i], cols = quad*4+q of bf[j])
#pragma unroll
        for (int i = 0; i < 4; i++)
#pragma unroll
          for (int j = 0; j < 4; j++)
            acc[i][j] = __builtin_amdgcn_mfma_f32_16x16x32_f16(bf[j], af[i], acc[i][j], 0, 0, 0);
      }
      __syncthreads();
    }
    // epilogue: one aligned 8B agent-scope atomic store per (i,j)
#pragma unroll
    for (int i = 0; i < 4; i++) {
      const long row = m0 + wm + i * 16 + nsub;
#pragma unroll
      for (int j = 0; j < 4; j++) {
        const int col = n0 + wn + j * 16 + (quad << 2);
        const float* bvp = &gbias[col];
        hpack4 pk;
#pragma unroll
        for (int q = 0; q < 4; q++) pk.h4[q] = (__fp16)(acc[i][j][q] + bvp[q]);
        __hip_atomic_store((unsigned long long*)(xp + row * (long)NN + col), pk.u,
                           __ATOMIC_RELAXED, __HIP_MEMORY_SCOPE_AGENT);
      }
    }
    return;
  }

  // ================= RNN part (round-8 body + group-pipelined wait) ========
  const int gi = bid & 3;           // d*2+g
  const int uo = bid >> 2;          // 0..15 unit-tile index
  const int d = gi >> 1, g = gi & 1;
  const int U0 = uo << 5;           // 32 units per WG
  const int mb = wv & 1, ut = wv >> 1;
  const int bq = (g << 5) + (mb << 4);   // wave's global batch base (16 rows)
  const int ul = (ut << 4) + nsub;       // wave's unit (local 0..31)

  // w_r fragments: direct global->reg hoist (round-11 proven), 64 VGPRs
  half8 wr_[16];
  {
    const float* wrbase = whh + ((long)d * GG + U0 + ul) * HH;
#pragma unroll
    for (int kk = 0; kk < 16; kk++) {
      const float* src = wrbase + (kk << 5) + (quad << 3);
      float4 a = *(const float4*)&src[0];
      float4 b = *(const float4*)&src[4];
      half8 o;
      o[0] = (__fp16)a.x; o[1] = (__fp16)a.y; o[2] = (__fp16)a.z; o[3] = (__fp16)a.w;
      o[4] = (__fp16)b.x; o[5] = (__fp16)b.y; o[6] = (__fp16)b.z; o[7] = (__fp16)b.w;
      wr_[kk] = o;
    }
  }
  // w_z / w_n in LDS fragment layout (round-11 proven, 0 conflicts):
  // Wf[idx][kk][lane], idx = gate*2 + utx (gate 0=z, 1=n)
  half8 (*Wf)[16][64] = (half8(*)[16][64])smem;
  for (int e = tid; e < 4096; e += 256) {
    int lane_e = e & 63;
    int kk = (e >> 6) & 15;
    int utx = (e >> 10) & 1;
    int gate = (e >> 11) & 1;
    int unit = U0 + (utx << 4) + (lane_e & 15);
    int col = (kk << 5) + ((lane_e >> 4) << 3);
    const float* src = whh + ((long)d * GG + (gate + 1) * HH + unit) * HH + col;
    float4 a = *(const float4*)&src[0];
    float4 b = *(const float4*)&src[4];
    half8 o;
    o[0] = (__fp16)a.x; o[1] = (__fp16)a.y; o[2] = (__fp16)a.z; o[3] = (__fp16)a.w;
    o[4] = (__fp16)b.x; o[5] = (__fp16)b.y; o[6] = (__fp16)b.z; o[7] = (__fp16)b.w;
    Wf[gate * 2 + utx][kk][lane_e] = o;
  }
  __syncthreads();

  const float bhr = bhh[d * GG + U0 + ul];
  const float bhz = bhh[d * GG + HH + U0 + ul];
  const float bhn = bhh[d * GG + 2 * HH + U0 + ul];

  // consumer per-lane ULL index within a 16KB hx block (per kk: +kk*128)
  const int cidx = ((quad >> 1) << 6) + (nsub << 2) + ((quad & 1) << 1);
  // producer per-lane ULL index: elem = uo*512 + ut*256 + r*16 + c4
  const int pr = lane & 15, pc4 = (lane >> 4) << 2;
  const int pidx = (uo << 7) + (ut << 6) + (pr << 2) + (pc4 >> 2);
  const int sh = (nsub & 3) << 4;   // xp granule half-extract shift
  // lane-constant offset of this lane's xp granule base within a timestep
  const long xoff = (long)(bq + (quad << 2)) * NN + d * GG + U0 + (ut << 4) + (nsub & 12);

  float hprev[4] = {0.f, 0.f, 0.f, 0.f};
  float pmax[4] = {-3e38f, -3e38f, -3e38f, -3e38f};
  hpack4 xw[12];                    // loop-carried prefetched xp granules

  // prefetch xp for step 0
  {
    const int tt0 = d ? (TLEN - 1) : 0;
    const __fp16* xb0 = xp + (long)(tt0 * BB) * NN + xoff;
#pragma unroll
    for (int i = 0; i < 4; i++) {
      const unsigned long long* q = (const unsigned long long*)(xb0 + (long)i * NN);
      xw[i * 3 + 0].u = __hip_atomic_load(&q[0], __ATOMIC_RELAXED, __HIP_MEMORY_SCOPE_AGENT);
      xw[i * 3 + 1].u = __hip_atomic_load(&q[HH / 4], __ATOMIC_RELAXED, __HIP_MEMORY_SCOPE_AGENT);
      xw[i * 3 + 2].u = __hip_atomic_load(&q[2 * HH / 4], __ATOMIC_RELAXED, __HIP_MEMORY_SCOPE_AGENT);
    }
  }

  for (int s = 0; s < TLEN; s++) {
    const int tt = d ? (TLEN - 1 - s) : s;
    const __fp16* xb0 = xp + (long)(tt * BB) * NN + xoff;   // for retry reloads
    const unsigned long long* hx8 = 0;
    hpack u[16];
    floatx4 ar0 = {0.f, 0.f, 0.f, 0.f}, ar1 = ar0, az0 = ar0, az1 = ar0, an0 = ar0, an1 = ar0;
    if (s > 0) {
      const int pt = d ? (tt + 1) : (tt - 1);
      hx8 = (const unsigned long long*)(hx + ((((long)pt * 2 + d) * 2 + g) * 2 + mb) * 8192);
      // h first attempt: issue ALL 32 loads (pipelined, coalesced)
#pragma unroll
      for (int kk = 0; kk < 16; kk++) {
        u[kk].u[0] = __hip_atomic_load(&hx8[kk * 128 + cidx], __ATOMIC_RELAXED, __HIP_MEMORY_SCOPE_AGENT);
        u[kk].u[1] = __hip_atomic_load(&hx8[kk * 128 + cidx + 1], __ATOMIC_RELAXED, __HIP_MEMORY_SCOPE_AGENT);
      }
      // GROUP-PIPELINED validate+MFMA: 4 groups x 4 kk. A straggler blocks
      // only its group; other groups' MFMA runs under its latency.
#pragma unroll
      for (int g4 = 0; g4 < 4; g4++) {
        int bad = 0;
#pragma unroll
        for (int kk = g4 * 4; kk < g4 * 4 + 4; kk++)
          bad |= (u[kk].u[0] == SENT) | (u[kk].u[1] == SENT);
        while (__any(bad)) {
#pragma unroll
          for (int kk = g4 * 4; kk < g4 * 4 + 4; kk++) {
            u[kk].u[0] = __hip_atomic_load(&hx8[kk * 128 + cidx], __ATOMIC_RELAXED, __HIP_MEMORY_SCOPE_AGENT);
            u[kk].u[1] = __hip_atomic_load(&hx8[kk * 128 + cidx + 1], __ATOMIC_RELAXED, __HIP_MEMORY_SCOPE_AGENT);
          }
          bad = 0;
#pragma unroll
          for (int kk = g4 * 4; kk < g4 * 4 + 4; kk++)
            bad |= (u[kk].u[0] == SENT) | (u[kk].u[1] == SENT);
        }
        // 12 MFMAs for this group (chain mapping unchanged: even->0, odd->1)
#pragma unroll
        for (int kk = g4 * 4; kk < g4 * 4 + 4; kk += 2) {
          half8 wzA = Wf[ut][kk][lane],     wnA = Wf[2 + ut][kk][lane];
          half8 wzB = Wf[ut][kk + 1][lane], wnB = Wf[2 + ut][kk + 1][lane];
          ar0 = __builtin_amdgcn_mfma_f32_16x16x32_f16(u[kk].v, wr_[kk], ar0, 0, 0, 0);
          az0 = __builtin_amdgcn_mfma_f32_16x16x32_f16(u[kk].v, wzA, az0, 0, 0, 0);
          an0 = __builtin_amdgcn_mfma_f32_16x16x32_f16(u[kk].v, wnA, an0, 0, 0, 0);
          ar1 = __builtin_amdgcn_mfma_f32_16x16x32_f16(u[kk + 1].v, wr_[kk + 1], ar1, 0, 0, 0);
          az1 = __builtin_amdgcn_mfma_f32_16x16x32_f16(u[kk + 1].v, wzB, az1, 0, 0, 0);
          an1 = __builtin_amdgcn_mfma_f32_16x16x32_f16(u[kk + 1].v, wnB, an1, 0, 0, 0);
        }
      }
    }
    // DEFERRED xp validation (epilogue-only inputs; prefetched a step ago)
    {
      int xbad = 0;
#pragma unroll
      for (int w = 0; w < 12; w++) xbad |= (xw[w].u == SENT);
      while (__any(xbad)) {
#pragma unroll
        for (int i = 0; i < 4; i++) {
          const unsigned long long* q = (const unsigned long long*)(xb0 + (long)i * NN);
          xw[i * 3 + 0].u = __hip_atomic_load(&q[0], __ATOMIC_RELAXED, __HIP_MEMORY_SCOPE_AGENT);
          xw[i * 3 + 1].u = __hip_atomic_load(&q[HH / 4], __ATOMIC_RELAXED, __HIP_MEMORY_SCOPE_AGENT);
          xw[i * 3 + 2].u = __hip_atomic_load(&q[2 * HH / 4], __ATOMIC_RELAXED, __HIP_MEMORY_SCOPE_AGENT);
        }
        xbad = 0;
#pragma unroll
        for (int w = 0; w < 12; w++) xbad |= (xw[w].u == SENT);
      }
    }
    // extract this lane's xp halves from the granules
    float xr[4], xz[4], xn[4];
#pragma unroll
    for (int i = 0; i < 4; i++) {
      hu16 t0, t1, t2;
      t0.s = (unsigned short)(xw[i * 3 + 0].u >> sh);
      t1.s = (unsigned short)(xw[i * 3 + 1].u >> sh);
      t2.s = (unsigned short)(xw[i * 3 + 2].u >> sh);
      xr[i] = (float)t0.h; xz[i] = (float)t1.h; xn[i] = (float)t2.h;
    }
    // epilogue: gates in fp32; h_old in registers (same lane wrote it)
#pragma unroll
    for (int i = 0; i < 4; i++) {
      float grv = ar0[i] + ar1[i] + xr[i] + bhr;
      float gzv = az0[i] + az1[i] + xz[i] + bhz;
      float gnv = an0[i] + an1[i] + bhn;        // recurrent part of n-gate (+b_hh)
      float rg = 1.f / (1.f + __expf(-grv));
      float zg = 1.f / (1.f + __expf(-gzv));
      float ex = __expf(2.f * (xn[i] + rg * gnv));
      float ng = 1.f - 2.f / (ex + 1.f);        // tanh
      float hv = (1.f - zg) * ng + zg * hprev[i];
      hprev[i] = hv;
      hst[wv][(quad << 2) + i][nsub] = (__fp16)hv;   // wave-local transpose stage
    }
    // COMPILER barrier: keep all hst DS writes before the DS read below
    // (in-order DS pipe per wave; TBAA lesson from rounds 1/3/4).
    asm volatile("" ::: "memory");
    // publish own 16x16 tile: hx via one 8B atomic store (wave's 64 lanes =
    // 512 consecutive bytes); hout (standard layout, nullable) plain store;
    // running max-pool of the SAME fp16-rounded values (nullable).
    {
      hpack4 pk;
      pk.h4 = *(const half4*)&hst[wv][pr][pc4];
      unsigned long long* hxw =
          (unsigned long long*)(hx + ((((long)tt * 2 + d) * 2 + g) * 2 + mb) * 8192);
      __hip_atomic_store(&hxw[pidx], pk.u, __ATOMIC_RELAXED, __HIP_MEMORY_SCOPE_AGENT);
      if (hout)
        *(half4*)&hout[(long)(tt * BB + (g << 5) + (mb << 4) + pr) * 1024 +
                       d * HH + U0 + (ut << 4) + pc4] = pk.h4;
      if (pooled) {
#pragma unroll
        for (int i = 0; i < 4; i++) pmax[i] = fmaxf(pmax[i], (float)pk.h4[i]);
      }
    }
    // PREFETCH xp for step s+1 (gemm far outruns consumption -> lands valid)
    if (s + 1 < TLEN) {
      const int tn = d ? (tt - 1) : (tt + 1);
      const __fp16* xbn = xp + (long)(tn * BB) * NN + xoff;
#pragma unroll
      for (int i = 0; i < 4; i++) {
        const unsigned long long* q = (const unsigned long long*)(xbn + (long)i * NN);
        xw[i * 3 + 0].u = __hip_atomic_load(&q[0], __ATOMIC_RELAXED, __HIP_MEMORY_SCOPE_AGENT);
        xw[i * 3 + 1].u = __hip_atomic_load(&q[HH / 4], __ATOMIC_RELAXED, __HIP_MEMORY_SCOPE_AGENT);
        xw[i * 3 + 2].u = __hip_atomic_load(&q[2 * HH / 4], __ATOMIC_RELAXED, __HIP_MEMORY_SCOPE_AGENT);
      }
    }
  }
  // write pooled result (lane owns row bq+pr, units U0+(ut<<4)+pc4 .. +3)
  if (pooled) {
    float4 o = {pmax[0], pmax[1], pmax[2], pmax[3]};
    *(float4*)&pooled[(long)((g << 5) + (mb << 4) + pr) * 1024 +
                      d * HH + U0 + (ut << 4) + pc4] = o;
  }
}

// ---- classifier head (pool already done in rnn1) ----
__global__ __launch_bounds__(128) void g2_head(const float* __restrict__ pooled,
                                               const float* __restrict__ w1,
                                               const float* __restrict__ b1,
                                               const float* __restrict__ w2,
                                               const float* __restrict__ b2,
                                               float* __restrict__ out) {
  __shared__ float pl[1024];
  __shared__ float hid[128];
  int b = blockIdx.x, j = threadIdx.x;
  for (int k = j; k < 1024; k += 128) pl[k] = pooled[b * 1024 + k];
  __syncthreads();
  float acc = b1[j];
  const float* wr = w1 + (long)j * 1024;
  for (int k = 0; k < 1024; k += 4) {
    float4 w = *(const float4*)&wr[k];
    acc += pl[k] * w.x + pl[k + 1] * w.y + pl[k + 2] * w.z + pl[k + 3] * w.w;
  }
  hid[j] = fmaxf(acc, 0.f);
  __syncthreads();
  if (j < 2) {
    float a = b2[j];
    for (int k = 0; k < 128; k++) a += hid[k] * w2[j * 128 + k];
    out[b * 2 + j] = a;
  }
}

extern "C" void kernel_launch(void* const* d_in, const int* in_sizes, int n_in,
                              void* d_out, int out_size, void* d_ws, size_t ws_size,
                              hipStream_t stream) {
  (void)in_sizes; (void)n_in; (void)out_size; (void)ws_size;
  const int* x = (const int*)d_in[0];
  const float* emb = (const float*)d_in[1];
  const float* w_ih0 = (const float*)d_in[2];
  const float* w_hh0 = (const float*)d_in[3];
  const float* b_ih0 = (const float*)d_in[4];
  const float* b_hh0 = (const float*)d_in[5];
  const float* w_ih1 = (const float*)d_in[6];
  const float* w_hh1 = (const float*)d_in[7];
  const float* b_ih1 = (const float*)d_in[8];
  const float* b_hh1 = (const float*)d_in[9];
  const float* w1 = (const float*)d_in[10];
  const float* b1 = (const float*)d_in[11];
  const float* w2 = (const float*)d_in[12];
  const float* b2 = (const float*)d_in[13];

  // ---- workspace layout ----
  //   fused0 (lay=0): gemm gathers emb/x + w_ih0 fp32 inline -> xp ∥
  //                   rnn0(hout=h0, hx=h1 region)
  //   fused1 (lay=1): gemm(h0, w_ih1 fp32) -> xp ∥ rnn1(hout=null,
  //                   hx=h1 re-armed, pooled out)
  //   head reads pooled.
  char* ws = (char*)d_ws;
  __fp16* xp = (__fp16*)(ws + 0);                  // 16384*3072*2 = 100,663,296
  __fp16* h0 = (__fp16*)(ws + 100663296);          // 16384*1024*2 =  33,554,432
  __fp16* h1 = (__fp16*)(ws + 134217728);          //                 33,554,432
  float* pooled = (float*)(ws + 167772160);        // 64*1024*4    =     262,144

  // sentinel-fill hx (h1) and xp: 0xFFFF per fp16 = -NaN, unreachable
  (void)hipMemsetAsync(h1, 0xFF, 33554432, stream);
  (void)hipMemsetAsync(xp, 0xFF, 100663296, stream);
  g2_fused<<<3136, 256, 0, stream>>>(w_hh0, b_hh0, xp, h0, h1,
                                     (const __fp16*)0, w_ih0, b_ih0, EPAD, 0,
                                     x, emb, (float*)0);
  // re-arm sentinels for layer 1 (h1's hx slots + xp)
  (void)hipMemsetAsync(h1, 0xFF, 33554432, stream);
  (void)hipMemsetAsync(xp, 0xFF, 100663296, stream);
  g2_fused<<<3136, 256, 0, stream>>>(w_hh1, b_hh1, xp, (__fp16*)0, h1,
                                     h0, w_ih1, b_ih1, 1024, 1,
                                     (const int*)0, (const float*)0, pooled);
  g2_head<<<64, 128, 0, stream>>>(pooled, w1, b1, w2, b2, (float*)d_out);
}

// Round 16
// 1942.386 us; speedup vs baseline: 1.1117x; 1.1117x over previous
//
#include <hip/hip_runtime.h>

// ---- problem constants ----
#define BB 64
#define TLEN 256
#define HH 512
#define GG 1536     // 3*H
#define EPAD 320    // E=300 padded to mult of 64
#define NN 3072     // 2*G (both directions stacked)
#define MM 16384    // T*B

typedef __attribute__((ext_vector_type(8))) __fp16 half8;
typedef __attribute__((ext_vector_type(4))) __fp16 half4;
typedef __attribute__((ext_vector_type(4))) float floatx4;

typedef union { unsigned long long u[2]; half8 v; } hpack;
typedef union { half4 h4; unsigned long long u; } hpack4;
typedef union { unsigned short s; __fp16 h; } hu16;

// ---- fused prep: padw (blocks 0..959) | cvt (960..2495) | embed (2496..7615) ----
// ROUND-15 LESSON: these conversions must stay AMORTIZED (once) — folding them
// into the gemm staging re-reads fp32 weights per m-tile (x128, 2x bytes) and
// made the fused kernel gemm-bound (908 -> 1074 us).
__global__ __launch_bounds__(256) void g2_prep(const int* __restrict__ x,
                                               const float* __restrict__ emb,
                                               __fp16* __restrict__ e,
                                               const float* __restrict__ w_ih0,
                                               __fp16* __restrict__ w0p,
                                               const float* __restrict__ w_ih1,
                                               __fp16* __restrict__ w1c) {
  const int blk = blockIdx.x;
  if (blk < 960) {                       // pad+convert w_ih0 [3072,300]->[3072,320]
    int idx = blk * 256 + threadIdx.x;   // total 3072*80
    int row = idx / 80;
    int c = idx - row * 80;
    half4 v = {0, 0, 0, 0};
    if (c < 75) {
      float4 f = *(const float4*)&w_ih0[(long)row * 300 + c * 4];
      v[0] = (__fp16)f.x; v[1] = (__fp16)f.y; v[2] = (__fp16)f.z; v[3] = (__fp16)f.w;
    }
    *(half4*)&w0p[row * EPAD + c * 4] = v;
  } else if (blk < 2496) {               // bulk fp32->fp16 of w_ih1 [3072,1024]
    long idx = (long)(blk - 960) * 256 + threadIdx.x;
    float4 a = *(const float4*)&w_ih1[idx * 8];
    float4 b = *(const float4*)&w_ih1[idx * 8 + 4];
    half8 o;
    o[0] = (__fp16)a.x; o[1] = (__fp16)a.y; o[2] = (__fp16)a.z; o[3] = (__fp16)a.w;
    o[4] = (__fp16)b.x; o[5] = (__fp16)b.y; o[6] = (__fp16)b.z; o[7] = (__fp16)b.w;
    *(half8*)&w1c[idx * 8] = o;
  } else {                               // embedding gather + K-pad + cvt
    int idx = (blk - 2496) * 256 + threadIdx.x;   // total 16384*80
    int row = idx / 80;
    int c = idx - row * 80;
    int t = row >> 6, b = row & 63;
    half4 v = {0, 0, 0, 0};
    if (c < 75) {
      int xi = x[b * TLEN + t];
      float4 f = *(const float4*)&emb[(long)xi * 300 + c * 4];
      v[0] = (__fp16)f.x; v[1] = (__fp16)f.y; v[2] = (__fp16)f.z; v[3] = (__fp16)f.w;
    }
    *(half4*)&e[row * EPAD + c * 4] = v;
  }
}

// ---- FUSED gemm + persistent GRU recurrence (one layer per launch) ----
// grid 3136 = 64 rnn WGs (blockIdx 0..63) + 3072 gemm WGs. The gemm computes
// xp = A x W^T + bias and publishes via 8B AGENT-SCOPE ATOMIC stores (must
// reach LLC — plain stores can sit in the producer XCD's L2 until kernel end
// -> circular wait). The rnn consumes xp[t] per step, validated by the proven
// sentinel-spin (xp can never be 0xFFFF = -NaN: finite dot + bias; fp16
// overflow gives +-inf, not NaN). DEADLOCK-FREE BY CAPACITY regardless of
// dispatch order (G16): rnn holds <=64 CUs, gemm always has >=192 ->
// unconditional progress.
//   * ROUND-14 (measured 908us/dispatch): GROUP-PIPELINED consumption — 16
//     h-fragments in 4 groups of 4 kk; validate group, run its 12 MFMAs,
//     next group. A straggler blocks only its group; other groups' MFMA runs
//     under its latency. Retries reload only the blocked group. xp validation
//     DEFERRED to after the MFMA loop (epilogue-only inputs).
//   * xp granules for step s+1 PREFETCHED at loop bottom (round-13).
//   * gemm m-tiles extremes-first (t pairs 0,255,1,254,...); inputs are
//     PRE-CONVERTED fp16 (round-15 lesson: keep conversions amortized).
//   * gemm epilogue OPERAND-SWAPPED (round-9 algebra): one aligned 8B word.
//   * rnn = round-8 body; weights in round-11's register-frugal layout (w_r
//     in 64 VGPRs, w_z/w_n in LDS fragment layout, 0 bank conflicts). LDS
//     UNIONED with gemm's As/Ws. hout nullable (layer 1); pooled nullable
//     (layer 0) — running fmax of the SAME fp16-rounded publish values is
//     bit-identical to pooling hx afterwards.
__global__ __launch_bounds__(256, 1) void g2_fused(
    const float* __restrict__ whh,    // [2][1536][512] fp32
    const float* __restrict__ bhh,    // [2][1536] fp32
    __fp16* xp,                       // [256][64][3072] gemm writes (atomic), rnn reads (atomic)
    __fp16* __restrict__ hout,        // [256][64][1024] or null
    __fp16* __restrict__ hx,          // [256][2][2][2][8192] (pre-memset 0xFF)
    const __fp16* __restrict__ ga,    // gemm A [16384][Kp] fp16
    const __fp16* __restrict__ gw,    // gemm W [3072][Kp] fp16
    const float* __restrict__ gbias,  // [3072]
    int Kp,
    float* __restrict__ pooled) {     // layer 1: [64][1024] fp32 out; else null
  __shared__ __align__(16) char smem[65536];
  __shared__ __fp16 hst[4][16][20];
  const unsigned long long SENT = 0xFFFFFFFFFFFFFFFFULL;
  const int bid = blockIdx.x;
  const int tid = threadIdx.x;
  const int lane = tid & 63, wv = tid >> 6;
  const int nsub = lane & 15, quad = lane >> 4;

  if (bid >= 64) {
    // ================= GEMM part: xp = ga x gw^T + gbias =================
    const int gb = bid - 64;
    const int kb = gb / 24, nb = gb - kb * 24;
    const int mt = (kb & 1) ? (127 - (kb >> 1)) : (kb >> 1);  // extremes first
    const int m0 = mt << 7, n0 = nb << 7;
    __fp16 (*As)[72] = (__fp16(*)[72])smem;
    __fp16 (*Ws)[72] = (__fp16(*)[72])(smem + 18432);
    const int wm = (wv >> 1) << 6, wn = (wv & 1) << 6;
    floatx4 acc[4][4];
#pragma unroll
    for (int i = 0; i < 4; i++)
#pragma unroll
      for (int j = 0; j < 4; j++) acc[i][j] = (floatx4){0.f, 0.f, 0.f, 0.f};
    const int lr = tid >> 3;          // 0..31
    const int lc = (tid & 7) << 3;    // 0..56 step 8
    for (int ko = 0; ko < Kp; ko += 64) {
#pragma unroll
      for (int p = 0; p < 4; p++) {
        int r = lr + p * 32;
        *(half8*)&As[r][lc] = *(const half8*)&ga[(long)(m0 + r) * Kp + ko + lc];
        *(half8*)&Ws[r][lc] = *(const half8*)&gw[(long)(n0 + r) * Kp + ko + lc];
      }
      __syncthreads();
#pragma unroll
      for (int kk = 0; kk < 64; kk += 32) {
        half8 af[4], bf[4];
        const int kr = kk + (quad << 3);
#pragma unroll
        for (int i = 0; i < 4; i++) af[i] = *(const half8*)&As[wm + i * 16 + nsub][kr];
#pragma unroll
        for (int j = 0; j < 4; j++) bf[j] = *(const half8*)&Ws[wn + j * 16 + nsub][kr];
        // SWAPPED: lane -> (row = nsub of af[i], cols = quad*4+q of bf[j])
#pragma unroll
        for (int i = 0; i < 4; i++)
#pragma unroll
          for (int j = 0; j < 4; j++)
            acc[i][j] = __builtin_amdgcn_mfma_f32_16x16x32_f16(bf[j], af[i], acc[i][j], 0, 0, 0);
      }
      __syncthreads();
    }
    // epilogue: one aligned 8B agent-scope atomic store per (i,j)
#pragma unroll
    for (int i = 0; i < 4; i++) {
      const long row = m0 + wm + i * 16 + nsub;
#pragma unroll
      for (int j = 0; j < 4; j++) {
        const int col = n0 + wn + j * 16 + (quad << 2);
        const float* bvp = &gbias[col];
        hpack4 pk;
#pragma unroll
        for (int q = 0; q < 4; q++) pk.h4[q] = (__fp16)(acc[i][j][q] + bvp[q]);
        __hip_atomic_store((unsigned long long*)(xp + row * (long)NN + col), pk.u,
                           __ATOMIC_RELAXED, __HIP_MEMORY_SCOPE_AGENT);
      }
    }
    return;
  }

  // ================= RNN part (round-8 body + group-pipelined wait) ========
  const int gi = bid & 3;           // d*2+g
  const int uo = bid >> 2;          // 0..15 unit-tile index
  const int d = gi >> 1, g = gi & 1;
  const int U0 = uo << 5;           // 32 units per WG
  const int mb = wv & 1, ut = wv >> 1;
  const int bq = (g << 5) + (mb << 4);   // wave's global batch base (16 rows)
  const int ul = (ut << 4) + nsub;       // wave's unit (local 0..31)

  // w_r fragments: direct global->reg hoist (round-11 proven), 64 VGPRs
  half8 wr_[16];
  {
    const float* wrbase = whh + ((long)d * GG + U0 + ul) * HH;
#pragma unroll
    for (int kk = 0; kk < 16; kk++) {
      const float* src = wrbase + (kk << 5) + (quad << 3);
      float4 a = *(const float4*)&src[0];
      float4 b = *(const float4*)&src[4];
      half8 o;
      o[0] = (__fp16)a.x; o[1] = (__fp16)a.y; o[2] = (__fp16)a.z; o[3] = (__fp16)a.w;
      o[4] = (__fp16)b.x; o[5] = (__fp16)b.y; o[6] = (__fp16)b.z; o[7] = (__fp16)b.w;
      wr_[kk] = o;
    }
  }
  // w_z / w_n in LDS fragment layout (round-11 proven, 0 conflicts):
  // Wf[idx][kk][lane], idx = gate*2 + utx (gate 0=z, 1=n)
  half8 (*Wf)[16][64] = (half8(*)[16][64])smem;
  for (int e = tid; e < 4096; e += 256) {
    int lane_e = e & 63;
    int kk = (e >> 6) & 15;
    int utx = (e >> 10) & 1;
    int gate = (e >> 11) & 1;
    int unit = U0 + (utx << 4) + (lane_e & 15);
    int col = (kk << 5) + ((lane_e >> 4) << 3);
    const float* src = whh + ((long)d * GG + (gate + 1) * HH + unit) * HH + col;
    float4 a = *(const float4*)&src[0];
    float4 b = *(const float4*)&src[4];
    half8 o;
    o[0] = (__fp16)a.x; o[1] = (__fp16)a.y; o[2] = (__fp16)a.z; o[3] = (__fp16)a.w;
    o[4] = (__fp16)b.x; o[5] = (__fp16)b.y; o[6] = (__fp16)b.z; o[7] = (__fp16)b.w;
    Wf[gate * 2 + utx][kk][lane_e] = o;
  }
  __syncthreads();

  const float bhr = bhh[d * GG + U0 + ul];
  const float bhz = bhh[d * GG + HH + U0 + ul];
  const float bhn = bhh[d * GG + 2 * HH + U0 + ul];

  // consumer per-lane ULL index within a 16KB hx block (per kk: +kk*128)
  const int cidx = ((quad >> 1) << 6) + (nsub << 2) + ((quad & 1) << 1);
  // producer per-lane ULL index: elem = uo*512 + ut*256 + r*16 + c4
  const int pr = lane & 15, pc4 = (lane >> 4) << 2;
  const int pidx = (uo << 7) + (ut << 6) + (pr << 2) + (pc4 >> 2);
  const int sh = (nsub & 3) << 4;   // xp granule half-extract shift
  // lane-constant offset of this lane's xp granule base within a timestep
  const long xoff = (long)(bq + (quad << 2)) * NN + d * GG + U0 + (ut << 4) + (nsub & 12);

  float hprev[4] = {0.f, 0.f, 0.f, 0.f};
  float pmax[4] = {-3e38f, -3e38f, -3e38f, -3e38f};
  hpack4 xw[12];                    // loop-carried prefetched xp granules

  // prefetch xp for step 0
  {
    const int tt0 = d ? (TLEN - 1) : 0;
    const __fp16* xb0 = xp + (long)(tt0 * BB) * NN + xoff;
#pragma unroll
    for (int i = 0; i < 4; i++) {
      const unsigned long long* q = (const unsigned long long*)(xb0 + (long)i * NN);
      xw[i * 3 + 0].u = __hip_atomic_load(&q[0], __ATOMIC_RELAXED, __HIP_MEMORY_SCOPE_AGENT);
      xw[i * 3 + 1].u = __hip_atomic_load(&q[HH / 4], __ATOMIC_RELAXED, __HIP_MEMORY_SCOPE_AGENT);
      xw[i * 3 + 2].u = __hip_atomic_load(&q[2 * HH / 4], __ATOMIC_RELAXED, __HIP_MEMORY_SCOPE_AGENT);
    }
  }

  for (int s = 0; s < TLEN; s++) {
    const int tt = d ? (TLEN - 1 - s) : s;
    const __fp16* xb0 = xp + (long)(tt * BB) * NN + xoff;   // for retry reloads
    const unsigned long long* hx8 = 0;
    hpack u[16];
    floatx4 ar0 = {0.f, 0.f, 0.f, 0.f}, ar1 = ar0, az0 = ar0, az1 = ar0, an0 = ar0, an1 = ar0;
    if (s > 0) {
      const int pt = d ? (tt + 1) : (tt - 1);
      hx8 = (const unsigned long long*)(hx + ((((long)pt * 2 + d) * 2 + g) * 2 + mb) * 8192);
      // h first attempt: issue ALL 32 loads (pipelined, coalesced)
#pragma unroll
      for (int kk = 0; kk < 16; kk++) {
        u[kk].u[0] = __hip_atomic_load(&hx8[kk * 128 + cidx], __ATOMIC_RELAXED, __HIP_MEMORY_SCOPE_AGENT);
        u[kk].u[1] = __hip_atomic_load(&hx8[kk * 128 + cidx + 1], __ATOMIC_RELAXED, __HIP_MEMORY_SCOPE_AGENT);
      }
      // GROUP-PIPELINED validate+MFMA: 4 groups x 4 kk. A straggler blocks
      // only its group; other groups' MFMA runs under its latency.
#pragma unroll
      for (int g4 = 0; g4 < 4; g4++) {
        int bad = 0;
#pragma unroll
        for (int kk = g4 * 4; kk < g4 * 4 + 4; kk++)
          bad |= (u[kk].u[0] == SENT) | (u[kk].u[1] == SENT);
        while (__any(bad)) {
#pragma unroll
          for (int kk = g4 * 4; kk < g4 * 4 + 4; kk++) {
            u[kk].u[0] = __hip_atomic_load(&hx8[kk * 128 + cidx], __ATOMIC_RELAXED, __HIP_MEMORY_SCOPE_AGENT);
            u[kk].u[1] = __hip_atomic_load(&hx8[kk * 128 + cidx + 1], __ATOMIC_RELAXED, __HIP_MEMORY_SCOPE_AGENT);
          }
          bad = 0;
#pragma unroll
          for (int kk = g4 * 4; kk < g4 * 4 + 4; kk++)
            bad |= (u[kk].u[0] == SENT) | (u[kk].u[1] == SENT);
        }
        // 12 MFMAs for this group (chain mapping unchanged: even->0, odd->1)
#pragma unroll
        for (int kk = g4 * 4; kk < g4 * 4 + 4; kk += 2) {
          half8 wzA = Wf[ut][kk][lane],     wnA = Wf[2 + ut][kk][lane];
          half8 wzB = Wf[ut][kk + 1][lane], wnB = Wf[2 + ut][kk + 1][lane];
          ar0 = __builtin_amdgcn_mfma_f32_16x16x32_f16(u[kk].v, wr_[kk], ar0, 0, 0, 0);
          az0 = __builtin_amdgcn_mfma_f32_16x16x32_f16(u[kk].v, wzA, az0, 0, 0, 0);
          an0 = __builtin_amdgcn_mfma_f32_16x16x32_f16(u[kk].v, wnA, an0, 0, 0, 0);
          ar1 = __builtin_amdgcn_mfma_f32_16x16x32_f16(u[kk + 1].v, wr_[kk + 1], ar1, 0, 0, 0);
          az1 = __builtin_amdgcn_mfma_f32_16x16x32_f16(u[kk + 1].v, wzB, az1, 0, 0, 0);
          an1 = __builtin_amdgcn_mfma_f32_16x16x32_f16(u[kk + 1].v, wnB, an1, 0, 0, 0);
        }
      }
    }
    // DEFERRED xp validation (epilogue-only inputs; prefetched a step ago)
    {
      int xbad = 0;
#pragma unroll
      for (int w = 0; w < 12; w++) xbad |= (xw[w].u == SENT);
      while (__any(xbad)) {
#pragma unroll
        for (int i = 0; i < 4; i++) {
          const unsigned long long* q = (const unsigned long long*)(xb0 + (long)i * NN);
          xw[i * 3 + 0].u = __hip_atomic_load(&q[0], __ATOMIC_RELAXED, __HIP_MEMORY_SCOPE_AGENT);
          xw[i * 3 + 1].u = __hip_atomic_load(&q[HH / 4], __ATOMIC_RELAXED, __HIP_MEMORY_SCOPE_AGENT);
          xw[i * 3 + 2].u = __hip_atomic_load(&q[2 * HH / 4], __ATOMIC_RELAXED, __HIP_MEMORY_SCOPE_AGENT);
        }
        xbad = 0;
#pragma unroll
        for (int w = 0; w < 12; w++) xbad |= (xw[w].u == SENT);
      }
    }
    // extract this lane's xp halves from the granules
    float xr[4], xz[4], xn[4];
#pragma unroll
    for (int i = 0; i < 4; i++) {
      hu16 t0, t1, t2;
      t0.s = (unsigned short)(xw[i * 3 + 0].u >> sh);
      t1.s = (unsigned short)(xw[i * 3 + 1].u >> sh);
      t2.s = (unsigned short)(xw[i * 3 + 2].u >> sh);
      xr[i] = (float)t0.h; xz[i] = (float)t1.h; xn[i] = (float)t2.h;
    }
    // epilogue: gates in fp32; h_old in registers (same lane wrote it)
#pragma unroll
    for (int i = 0; i < 4; i++) {
      float grv = ar0[i] + ar1[i] + xr[i] + bhr;
      float gzv = az0[i] + az1[i] + xz[i] + bhz;
      float gnv = an0[i] + an1[i] + bhn;        // recurrent part of n-gate (+b_hh)
      float rg = 1.f / (1.f + __expf(-grv));
      float zg = 1.f / (1.f + __expf(-gzv));
      float ex = __expf(2.f * (xn[i] + rg * gnv));
      float ng = 1.f - 2.f / (ex + 1.f);        // tanh
      float hv = (1.f - zg) * ng + zg * hprev[i];
      hprev[i] = hv;
      hst[wv][(quad << 2) + i][nsub] = (__fp16)hv;   // wave-local transpose stage
    }
    // COMPILER barrier: keep all hst DS writes before the DS read below
    // (in-order DS pipe per wave; TBAA lesson from rounds 1/3/4).
    asm volatile("" ::: "memory");
    // publish own 16x16 tile: hx via one 8B atomic store (wave's 64 lanes =
    // 512 consecutive bytes); hout (standard layout, nullable) plain store;
    // running max-pool of the SAME fp16-rounded values (nullable).
    {
      hpack4 pk;
      pk.h4 = *(const half4*)&hst[wv][pr][pc4];
      unsigned long long* hxw =
          (unsigned long long*)(hx + ((((long)tt * 2 + d) * 2 + g) * 2 + mb) * 8192);
      __hip_atomic_store(&hxw[pidx], pk.u, __ATOMIC_RELAXED, __HIP_MEMORY_SCOPE_AGENT);
      if (hout)
        *(half4*)&hout[(long)(tt * BB + (g << 5) + (mb << 4) + pr) * 1024 +
                       d * HH + U0 + (ut << 4) + pc4] = pk.h4;
      if (pooled) {
#pragma unroll
        for (int i = 0; i < 4; i++) pmax[i] = fmaxf(pmax[i], (float)pk.h4[i]);
      }
    }
    // PREFETCH xp for step s+1 (gemm far outruns consumption -> lands valid)
    if (s + 1 < TLEN) {
      const int tn = d ? (tt - 1) : (tt + 1);
      const __fp16* xbn = xp + (long)(tn * BB) * NN + xoff;
#pragma unroll
      for (int i = 0; i < 4; i++) {
        const unsigned long long* q = (const unsigned long long*)(xbn + (long)i * NN);
        xw[i * 3 + 0].u = __hip_atomic_load(&q[0], __ATOMIC_RELAXED, __HIP_MEMORY_SCOPE_AGENT);
        xw[i * 3 + 1].u = __hip_atomic_load(&q[HH / 4], __ATOMIC_RELAXED, __HIP_MEMORY_SCOPE_AGENT);
        xw[i * 3 + 2].u = __hip_atomic_load(&q[2 * HH / 4], __ATOMIC_RELAXED, __HIP_MEMORY_SCOPE_AGENT);
      }
    }
  }
  // write pooled result (lane owns row bq+pr, units U0+(ut<<4)+pc4 .. +3)
  if (pooled) {
    float4 o = {pmax[0], pmax[1], pmax[2], pmax[3]};
    *(float4*)&pooled[(long)((g << 5) + (mb << 4) + pr) * 1024 +
                      d * HH + U0 + (ut << 4) + pc4] = o;
  }
}

// ---- classifier head (pool already done in rnn1) ----
__global__ __launch_bounds__(128) void g2_head(const float* __restrict__ pooled,
                                               const float* __restrict__ w1,
                                               const float* __restrict__ b1,
                                               const float* __restrict__ w2,
                                               const float* __restrict__ b2,
                                               float* __restrict__ out) {
  __shared__ float pl[1024];
  __shared__ float hid[128];
  int b = blockIdx.x, j = threadIdx.x;
  for (int k = j; k < 1024; k += 128) pl[k] = pooled[b * 1024 + k];
  __syncthreads();
  float acc = b1[j];
  const float* wr = w1 + (long)j * 1024;
  for (int k = 0; k < 1024; k += 4) {
    float4 w = *(const float4*)&wr[k];
    acc += pl[k] * w.x + pl[k + 1] * w.y + pl[k + 2] * w.z + pl[k + 3] * w.w;
  }
  hid[j] = fmaxf(acc, 0.f);
  __syncthreads();
  if (j < 2) {
    float a = b2[j];
    for (int k = 0; k < 128; k++) a += hid[k] * w2[j * 128 + k];
    out[b * 2 + j] = a;
  }
}

extern "C" void kernel_launch(void* const* d_in, const int* in_sizes, int n_in,
                              void* d_out, int out_size, void* d_ws, size_t ws_size,
                              hipStream_t stream) {
  (void)in_sizes; (void)n_in; (void)out_size; (void)ws_size;
  const int* x = (const int*)d_in[0];
  const float* emb = (const float*)d_in[1];
  const float* w_ih0 = (const float*)d_in[2];
  const float* w_hh0 = (const float*)d_in[3];
  const float* b_ih0 = (const float*)d_in[4];
  const float* b_hh0 = (const float*)d_in[5];
  const float* w_ih1 = (const float*)d_in[6];
  const float* w_hh1 = (const float*)d_in[7];
  const float* b_ih1 = (const float*)d_in[8];
  const float* b_hh1 = (const float*)d_in[9];
  const float* w1 = (const float*)d_in[10];
  const float* b1 = (const float*)d_in[11];
  const float* w2 = (const float*)d_in[12];
  const float* b2 = (const float*)d_in[13];

  // ---- workspace layout (total <= 186,785,792 B) ----
  //   fused0: gemm(e_pad,w0p)->xp ∥ rnn0(hout=h0, hx=h1 region)
  //   fused1: gemm(h0,w1c)->xp   ∥ rnn1(hout=null, hx=h1 re-armed, pooled out)
  //   head reads pooled.
  char* ws = (char*)d_ws;
  __fp16* xp = (__fp16*)(ws + 0);                  // 16384*3072*2 = 100,663,296
  __fp16* h0 = (__fp16*)(ws + 100663296);          // 16384*1024*2 =  33,554,432
  __fp16* h1 = (__fp16*)(ws + 134217728);          //                 33,554,432
  __fp16* e_pad = (__fp16*)(ws + 167772160);       // 16384*320*2  =  10,485,760
  __fp16* w0p = (__fp16*)(ws + 178257920);         // 3072*320*2   =   1,966,080
  __fp16* w1c = (__fp16*)(ws + 180224000);         // 3072*1024*2  =   6,291,456
  float* pooled = (float*)(ws + 186515456);        // 64*1024*4    =     262,144

  // sentinel-fill hx (h1) and xp: 0xFFFF per fp16 = -NaN, unreachable
  (void)hipMemsetAsync(h1, 0xFF, 33554432, stream);
  (void)hipMemsetAsync(xp, 0xFF, 100663296, stream);
  g2_prep<<<7616, 256, 0, stream>>>(x, emb, e_pad, w_ih0, w0p, w_ih1, w1c);
  g2_fused<<<3136, 256, 0, stream>>>(w_hh0, b_hh0, xp, h0, h1, e_pad, w0p,
                                     b_ih0, EPAD, (float*)0);
  // re-arm sentinels for layer 1 (h1's hx slots + xp)
  (void)hipMemsetAsync(h1, 0xFF, 33554432, stream);
  (void)hipMemsetAsync(xp, 0xFF, 100663296, stream);
  g2_fused<<<3136, 256, 0, stream>>>(w_hh1, b_hh1, xp, (__fp16*)0, h1, h0, w1c,
                                     b_ih1, 1024, pooled);
  g2_head<<<64, 128, 0, stream>>>(pooled, w1, b1, w2, b2, (float*)d_out);
}